// Round 5
// baseline (7936.425 us; speedup 1.0000x reference)
//
#include <hip/hip_runtime.h>

// DeepLSTM persistent wavefront pipeline for MI355X (gfx950).
// 256 WGs (1/CU): layer = blockIdx/64, slice of 8 hidden units = blockIdx%64.
// Weights resident in LDS as hi/lo bf16 split.
// R5: FLAG-FREE sync. hbuf is NaN-poisoned (0xFF) each launch; producers
// fire-and-forget agent-scope 2B h-stores; consumers poll the h data itself
// (agent-scope 8B atomic loads) until no 0xFFFF halfword remains. Detection
// and data arrive in the same round trip: no vmcnt drain, no flag store,
// no flag poll -- ~2 fewer serialized MALL round trips per pipeline hop.

constexpr int Bv = 32;
constexpr int Tv = 512;
constexpr int Iv = 256;
constexpr int Hv = 512;
constexpr int LAYv = 4;
constexpr int SLICES = 64;   // WGs per layer
constexpr int THREADS = 256; // 4 waves
constexpr int NKK = 32;      // max K/32 (512 recurrent + 512 input)
constexpr int WTAB = 2 * NKK * 64 * 8;            // shorts per weight table (32768)
constexpr unsigned SMEM_BYTES = WTAB * 2 * 2 + 32 * 33 * 4; // 135296

typedef short sfrag __attribute__((ext_vector_type(8)));
typedef float facc  __attribute__((ext_vector_type(4)));
typedef float f32x4 __attribute__((ext_vector_type(4)));

struct Params {
  const float *x;
  const float *Wx0i, *Wx0f, *Wx0o, *Wx0c;
  const float *Wxi, *Wxf, *Wxo, *Wxc;
  const float *Whi, *Whf, *Who, *Whc;
  const float *bi, *bf, *bo, *bc;
  float *out;
  unsigned short *hbuf; // [(T+1)][L][B][H] bf16 slots, NaN-poisoned
};

__device__ __forceinline__ unsigned short f2bf(float f) {
  unsigned int u = __builtin_bit_cast(unsigned int, f);
  u += 0x7FFFu + ((u >> 16) & 1u); // RNE
  return (unsigned short)(u >> 16);
}
__device__ __forceinline__ float bf2f(unsigned short s) {
  unsigned int u = ((unsigned int)s) << 16;
  return __builtin_bit_cast(float, u);
}

// true if any 16-bit halfword of the fragment is 0xFFFF (bf16 NaN poison)
__device__ __forceinline__ bool frag_has_poison(sfrag f) {
  bool bad = false;
#pragma unroll
  for (int j = 0; j < 8; ++j) bad |= (f[j] == (short)-1);
  return bad;
}

// 16B agent-coherent load (bypasses stale L1/L2; sees other XCDs' stores)
__device__ __forceinline__ sfrag ld16_agent(const unsigned short *ptr) {
  const unsigned long long *q = (const unsigned long long *)ptr;
  union { unsigned long long u[2]; sfrag s; } r;
  r.u[0] = __hip_atomic_load(q, __ATOMIC_RELAXED, __HIP_MEMORY_SCOPE_AGENT);
  r.u[1] = __hip_atomic_load(q + 1, __ATOMIC_RELAXED, __HIP_MEMORY_SCOPE_AGENT);
  return r.s;
}

// Poll all 16 fragments of one A-row until every halfword is non-poison.
// Data is stable once valid, so re-loads of valid fragments are harmless;
// we only re-load still-poisoned ones.
__device__ __forceinline__ void poll_frags(sfrag (&a)[16],
                                           const unsigned short *base, int kgrp) {
  unsigned pend = 0xFFFFu;
  do {
#pragma unroll
    for (int kk = 0; kk < 16; ++kk)
      if (pend & (1u << kk))
        a[kk] = ld16_agent(base + kk * 32 + kgrp * 8);
#pragma unroll
    for (int kk = 0; kk < 16; ++kk)
      if (pend & (1u << kk))
        if (!frag_has_poison(a[kk])) pend &= ~(1u << kk);
    if (pend) __builtin_amdgcn_s_sleep(1);
  } while (pend);
}

__global__ void __launch_bounds__(THREADS, 1) lstm_pipeline(Params p) {
  const int wg = blockIdx.x;
  const int l = wg >> 6;       // layer 0..3
  const int slice = wg & 63;   // 8-unit slice
  const int tid = threadIdx.x;
  const int lane = tid & 63;
  const int w = tid >> 6;      // wave 0..3
  const int mt = w & 1;        // M-tile (batch 16-block)
  const int nt = w >> 1;       // N-tile (gate-col 16-block)

  extern __shared__ char smem[];
  unsigned short *wlds_hi = (unsigned short *)smem;          // [2][32][64][8]
  unsigned short *wlds_lo = wlds_hi + WTAB;
  float *preact = (float *)(smem + (size_t)WTAB * 2 * 2);    // [32][33]

  // gate-indexed weight bases for this layer
  const float *Wh[4] = {p.Whi + (size_t)l * Hv * Hv, p.Whf + (size_t)l * Hv * Hv,
                        p.Who + (size_t)l * Hv * Hv, p.Whc + (size_t)l * Hv * Hv};
  const float *Wx[4];
  if (l == 0) { Wx[0] = p.Wx0i; Wx[1] = p.Wx0f; Wx[2] = p.Wx0o; Wx[3] = p.Wx0c; }
  else {
    size_t o = (size_t)(l - 1) * Hv * Hv;
    Wx[0] = p.Wxi + o; Wx[1] = p.Wxf + o; Wx[2] = p.Wxo + o; Wx[3] = p.Wxc + o;
  }
  const int kx_max = (l == 0) ? Iv : Hv;

  // ---- stage weight slice into LDS in MFMA B-fragment order (hi/lo split) ----
  for (int idx = tid; idx < 2 * NKK * 64; idx += THREADS) {
    int lanei = idx & 63;
    int kk = (idx >> 6) & (NKK - 1);
    int nti = idx >> 11;
    int kbase = kk * 32 + (lanei >> 4) * 8;
    int n = nti * 16 + (lanei & 15); // gate-col within 32: n = jj*4 + g
    int jj = n >> 2, g = n & 3;
    int col = slice * 8 + jj;
    sfrag vh, vl;
#pragma unroll
    for (int j = 0; j < 8; ++j) {
      int k = kbase + j;
      float wv;
      if (k < Hv) wv = Wh[g][(size_t)k * Hv + col];
      else {
        int kx = k - Hv;
        wv = (kx < kx_max) ? Wx[g][(size_t)kx * Hv + col] : 0.f;
      }
      unsigned short h16 = f2bf(wv);
      vh[j] = (short)h16;
      vl[j] = (short)f2bf(wv - bf2f(h16));
    }
    *(sfrag *)&wlds_hi[(size_t)idx * 8] = vh;
    *(sfrag *)&wlds_lo[(size_t)idx * 8] = vl;
  }

  // epilogue thread mapping: bm = batch, um = unit-in-slice
  const int bm = tid >> 3;
  const int um = tid & 7;
  const int jg = slice * 8 + um;
  const float bia_i = p.bi[l * Hv + jg];
  const float bia_f = p.bf[l * Hv + jg];
  const float bia_o = p.bo[l * Hv + jg];
  const float bia_c = p.bc[l * Hv + jg];
  float cstate = 0.f;

  __syncthreads();

  const int m = mt * 16 + (lane & 15); // batch row for A fragment
  const int kgrp = lane >> 4;          // k-group 0..3
  unsigned short *hbuf = p.hbuf;

#define MFMA_BURST(A, KKB, CNT)                                                \
  {                                                                            \
    _Pragma("unroll") for (int j = 0; j < (CNT); ++j) {                        \
      sfrag bh =                                                               \
          *(const sfrag *)&wlds_hi[(size_t)((nt * NKK + (KKB) + j) * 64 + lane) * 8]; \
      sfrag bl =                                                               \
          *(const sfrag *)&wlds_lo[(size_t)((nt * NKK + (KKB) + j) * 64 + lane) * 8]; \
      acc0 = __builtin_amdgcn_mfma_f32_16x16x32_bf16(A[j], bh, acc0, 0, 0, 0); \
      acc1 = __builtin_amdgcn_mfma_f32_16x16x32_bf16(A[j], bl, acc1, 0, 0, 0); \
    }                                                                          \
  }

  for (int t = 0; t < Tv; ++t) {
    facc acc0 = {0.f, 0.f, 0.f, 0.f};
    facc acc1 = {0.f, 0.f, 0.f, 0.f};

    // ---- recurrent input: poll h[t][l] (data is its own ready flag) ----
    const unsigned short *hrec =
        hbuf + ((size_t)(t * LAYv + l) * Bv * Hv) + (size_t)m * Hv;
    sfrag arec[16];
    poll_frags(arec, hrec, kgrp);

    // ---- layer input ----
    sfrag ain[16];
    int nin;
    if (l == 0) {
      const float *xbp = p.x + ((size_t)m * Tv + t) * Iv + kgrp * 8;
#pragma unroll
      for (int kk = 0; kk < 8; ++kk) {
        f32x4 lo = *(const f32x4 *)(xbp + kk * 32);
        f32x4 hi = *(const f32x4 *)(xbp + kk * 32 + 4);
#pragma unroll
        for (int j = 0; j < 4; ++j) {
          ain[kk][j] = (short)f2bf(lo[j]);
          ain[kk][4 + j] = (short)f2bf(hi[j]);
        }
      }
      nin = 8;
    } else {
      const unsigned short *hin =
          hbuf + ((size_t)((t + 1) * LAYv + (l - 1)) * Bv * Hv) + (size_t)m * Hv;
      poll_frags(ain, hin, kgrp);
      nin = 16;
    }

    // ---- GEMM [32 x K] * [K x 32], hi+lo weight tables ----
    MFMA_BURST(arec, 0, 16)
    if (nin == 8) { MFMA_BURST(ain, 16, 8) }
    else          { MFMA_BURST(ain, 16, 16) }

    // ---- scatter pre-activations to LDS ----
    __syncthreads(); // previous step's epilogue reads of preact are done
    {
      int row = mt * 16 + kgrp * 4;
      int coln = nt * 16 + (lane & 15);
#pragma unroll
      for (int r = 0; r < 4; ++r)
        preact[(row + r) * 33 + coln] = acc0[r] + acc1[r];
    }
    __syncthreads();

    // ---- gates / state update: one thread per (batch, unit) ----
    float pi = preact[bm * 33 + um * 4 + 0] + bia_i;
    float pf = preact[bm * 33 + um * 4 + 1] + bia_f;
    float po = preact[bm * 33 + um * 4 + 2] + bia_o;
    float pc = preact[bm * 33 + um * 4 + 3] + bia_c;
    float gi = 1.f / (1.f + __expf(-pi));
    float gf = 1.f / (1.f + __expf(-pf));
    float go = 1.f / (1.f + __expf(-po));
    float gc = tanhf(pc);
    cstate = gf * cstate + gi * gc;
    float hval = go * tanhf(cstate);

    // fire-and-forget agent-scope store: the data IS the ready flag
    __hip_atomic_store(
        &hbuf[(size_t)((t + 1) * LAYv + l) * Bv * Hv + (size_t)bm * Hv + jg],
        f2bf(hval), __ATOMIC_RELAXED, __HIP_MEMORY_SCOPE_AGENT);
    if (l == LAYv - 1)
      p.out[((size_t)bm * Tv + t) * Hv + jg] = hval;
    // no drain, no flag store -- next consumers detect via the data itself
  }
#undef MFMA_BURST
}

extern "C" void kernel_launch(void *const *d_in, const int *in_sizes, int n_in,
                              void *d_out, int out_size, void *d_ws, size_t ws_size,
                              hipStream_t stream) {
  Params prm;
  prm.x = (const float *)d_in[0];
  prm.Wx0i = (const float *)d_in[1];
  prm.Wx0f = (const float *)d_in[2];
  prm.Wx0o = (const float *)d_in[3];
  prm.Wx0c = (const float *)d_in[4];
  prm.Wxi = (const float *)d_in[5];
  prm.Wxf = (const float *)d_in[6];
  prm.Wxo = (const float *)d_in[7];
  prm.Wxc = (const float *)d_in[8];
  prm.Whi = (const float *)d_in[9];
  prm.Whf = (const float *)d_in[10];
  prm.Who = (const float *)d_in[11];
  prm.Whc = (const float *)d_in[12];
  prm.bi = (const float *)d_in[13];
  prm.bf = (const float *)d_in[14];
  prm.bo = (const float *)d_in[15];
  prm.bc = (const float *)d_in[16];
  prm.out = (float *)d_out;

  size_t hbytes = (size_t)(Tv + 1) * LAYv * Bv * Hv * sizeof(unsigned short);
  if (ws_size < hbytes) return;
  prm.hbuf = (unsigned short *)d_ws;

  // Poison entire h history to bf16 NaN (0xFFFF), then make t=0 slot valid
  // zeros. Both are graph-captured stream ops -> deterministic per replay.
  hipMemsetAsync(d_ws, 0xFF, hbytes, stream);
  hipMemsetAsync(d_ws, 0x00, (size_t)LAYv * Bv * Hv * sizeof(unsigned short),
                 stream);

  hipFuncSetAttribute(reinterpret_cast<const void *>(lstm_pipeline),
                      hipFuncAttributeMaxDynamicSharedMemorySize, (int)SMEM_BYTES);

  // Plain launch: 135KB LDS forces 1 block/CU; grid == 256 == #CUs, so all
  // blocks are co-resident.
  hipLaunchKernelGGL(lstm_pipeline, dim3(LAYv * SLICES), dim3(THREADS),
                     SMEM_BYTES, stream, prm);
}

// Round 6
// 4852.486 us; speedup vs baseline: 1.6355x; 1.6355x over previous
//
#include <hip/hip_runtime.h>

// DeepLSTM persistent wavefront pipeline for MI355X (gfx950).
// 256 WGs (1/CU): layer = blockIdx/64, slice of 8 hidden units = blockIdx%64.
// Weights resident in LDS as hi/lo bf16 split.
// R6: ALL cross-WG communication uses inline-asm sc0+sc1 (full L1+L2 bypass)
// loads/stores. Theory: __hip_atomic_load(AGENT) polls were hitting stale
// per-CU L1 lines; progress was governed by L1 eviction (~10us/hop floor,
// rare-eviction outliers = 27ms replays). Bypass polls observe the MALL
// coherence point directly -> hop should drop to a few fabric RTs.

constexpr int Bv = 32;
constexpr int Tv = 512;
constexpr int Iv = 256;
constexpr int Hv = 512;
constexpr int LAYv = 4;
constexpr int SLICES = 64;   // WGs per layer
constexpr int THREADS = 256; // 4 waves
constexpr int NKK = 32;      // max K/32 (512 recurrent + 512 input)
constexpr int WTAB = 2 * NKK * 64 * 8;            // shorts per weight table (32768)
constexpr unsigned SMEM_BYTES = WTAB * 2 * 2 + 32 * 33 * 4; // 135296

typedef short sfrag __attribute__((ext_vector_type(8)));
typedef int   i32x4 __attribute__((ext_vector_type(4)));
typedef float facc  __attribute__((ext_vector_type(4)));
typedef float f32x4 __attribute__((ext_vector_type(4)));

struct Params {
  const float *x;
  const float *Wx0i, *Wx0f, *Wx0o, *Wx0c;
  const float *Wxi, *Wxf, *Wxo, *Wxc;
  const float *Whi, *Whf, *Who, *Whc;
  const float *bi, *bf, *bo, *bc;
  float *out;
  unsigned short *hbuf; // [(T+1)][L][B][H] bf16 slots
  int *flags;           // per_slice: [(T+1)][L][SLICES] else [(T+1)][L]
  int per_slice;
};

__device__ __forceinline__ unsigned short f2bf(float f) {
  unsigned int u = __builtin_bit_cast(unsigned int, f);
  u += 0x7FFFu + ((u >> 16) & 1u); // RNE
  return (unsigned short)(u >> 16);
}
__device__ __forceinline__ float bf2f(unsigned short s) {
  unsigned int u = ((unsigned int)s) << 16;
  return __builtin_bit_cast(float, u);
}

// ---- full-bypass (L1+L2) primitives: fresh data from the MALL every time ----
__device__ __forceinline__ int ld_flag_bypass(const int *p) {
  int v;
  asm volatile("global_load_dword %0, %1, off sc0 sc1\n\t"
               "s_waitcnt vmcnt(0)"
               : "=v"(v) : "v"(p) : "memory");
  return v;
}
__device__ __forceinline__ void st_short_bypass(unsigned short *p, unsigned short v) {
  asm volatile("global_store_short %0, %1, off sc0 sc1" ::"v"(p), "v"(v)
               : "memory");
}
__device__ __forceinline__ void st_dword_bypass(int *p, int v) {
  asm volatile("global_store_dword %0, %1, off sc0 sc1" ::"v"(p), "v"(v)
               : "memory");
}

// 16 x 16B bypass loads of one A-row (fragments kk=0..15 at 64B stride),
// with the vmcnt(0) INSIDE the asm so no consumer can be scheduled before
// the data is architecturally ready.
__device__ __forceinline__ void ld_row_bypass(sfrag (&a)[16],
                                              const unsigned short *base) {
  i32x4 r0, r1, r2, r3, r4, r5, r6, r7, r8, r9, r10, r11, r12, r13, r14, r15;
  asm volatile(
      "global_load_dwordx4 %0, %16, off sc0 sc1\n\t"
      "global_load_dwordx4 %1, %16, off offset:64 sc0 sc1\n\t"
      "global_load_dwordx4 %2, %16, off offset:128 sc0 sc1\n\t"
      "global_load_dwordx4 %3, %16, off offset:192 sc0 sc1\n\t"
      "global_load_dwordx4 %4, %16, off offset:256 sc0 sc1\n\t"
      "global_load_dwordx4 %5, %16, off offset:320 sc0 sc1\n\t"
      "global_load_dwordx4 %6, %16, off offset:384 sc0 sc1\n\t"
      "global_load_dwordx4 %7, %16, off offset:448 sc0 sc1\n\t"
      "global_load_dwordx4 %8, %16, off offset:512 sc0 sc1\n\t"
      "global_load_dwordx4 %9, %16, off offset:576 sc0 sc1\n\t"
      "global_load_dwordx4 %10, %16, off offset:640 sc0 sc1\n\t"
      "global_load_dwordx4 %11, %16, off offset:704 sc0 sc1\n\t"
      "global_load_dwordx4 %12, %16, off offset:768 sc0 sc1\n\t"
      "global_load_dwordx4 %13, %16, off offset:832 sc0 sc1\n\t"
      "global_load_dwordx4 %14, %16, off offset:896 sc0 sc1\n\t"
      "global_load_dwordx4 %15, %16, off offset:960 sc0 sc1\n\t"
      "s_waitcnt vmcnt(0)"
      : "=&v"(r0), "=&v"(r1), "=&v"(r2), "=&v"(r3), "=&v"(r4), "=&v"(r5),
        "=&v"(r6), "=&v"(r7), "=&v"(r8), "=&v"(r9), "=&v"(r10), "=&v"(r11),
        "=&v"(r12), "=&v"(r13), "=&v"(r14), "=&v"(r15)
      : "v"(base)
      : "memory");
  a[0] = __builtin_bit_cast(sfrag, r0);   a[1] = __builtin_bit_cast(sfrag, r1);
  a[2] = __builtin_bit_cast(sfrag, r2);   a[3] = __builtin_bit_cast(sfrag, r3);
  a[4] = __builtin_bit_cast(sfrag, r4);   a[5] = __builtin_bit_cast(sfrag, r5);
  a[6] = __builtin_bit_cast(sfrag, r6);   a[7] = __builtin_bit_cast(sfrag, r7);
  a[8] = __builtin_bit_cast(sfrag, r8);   a[9] = __builtin_bit_cast(sfrag, r9);
  a[10] = __builtin_bit_cast(sfrag, r10); a[11] = __builtin_bit_cast(sfrag, r11);
  a[12] = __builtin_bit_cast(sfrag, r12); a[13] = __builtin_bit_cast(sfrag, r13);
  a[14] = __builtin_bit_cast(sfrag, r14); a[15] = __builtin_bit_cast(sfrag, r15);
}

__global__ void __launch_bounds__(THREADS, 1) lstm_pipeline(Params p) {
  const int wg = blockIdx.x;
  const int l = wg >> 6;       // layer 0..3
  const int slice = wg & 63;   // 8-unit slice
  const int tid = threadIdx.x;
  const int lane = tid & 63;
  const int w = tid >> 6;      // wave 0..3
  const int mt = w & 1;        // M-tile (batch 16-block)
  const int nt = w >> 1;       // N-tile (gate-col 16-block)

  extern __shared__ char smem[];
  unsigned short *wlds_hi = (unsigned short *)smem;          // [2][32][64][8]
  unsigned short *wlds_lo = wlds_hi + WTAB;
  float *preact = (float *)(smem + (size_t)WTAB * 2 * 2);    // [32][33]

  // gate-indexed weight bases for this layer
  const float *Wh[4] = {p.Whi + (size_t)l * Hv * Hv, p.Whf + (size_t)l * Hv * Hv,
                        p.Who + (size_t)l * Hv * Hv, p.Whc + (size_t)l * Hv * Hv};
  const float *Wx[4];
  if (l == 0) { Wx[0] = p.Wx0i; Wx[1] = p.Wx0f; Wx[2] = p.Wx0o; Wx[3] = p.Wx0c; }
  else {
    size_t o = (size_t)(l - 1) * Hv * Hv;
    Wx[0] = p.Wxi + o; Wx[1] = p.Wxf + o; Wx[2] = p.Wxo + o; Wx[3] = p.Wxc + o;
  }
  const int kx_max = (l == 0) ? Iv : Hv;

  // ---- stage weight slice into LDS in MFMA B-fragment order (hi/lo split) ----
  for (int idx = tid; idx < 2 * NKK * 64; idx += THREADS) {
    int lanei = idx & 63;
    int kk = (idx >> 6) & (NKK - 1);
    int nti = idx >> 11;
    int kbase = kk * 32 + (lanei >> 4) * 8;
    int n = nti * 16 + (lanei & 15); // gate-col within 32: n = jj*4 + g
    int jj = n >> 2, g = n & 3;
    int col = slice * 8 + jj;
    sfrag vh, vl;
#pragma unroll
    for (int j = 0; j < 8; ++j) {
      int k = kbase + j;
      float wv;
      if (k < Hv) wv = Wh[g][(size_t)k * Hv + col];
      else {
        int kx = k - Hv;
        wv = (kx < kx_max) ? Wx[g][(size_t)kx * Hv + col] : 0.f;
      }
      unsigned short h16 = f2bf(wv);
      vh[j] = (short)h16;
      vl[j] = (short)f2bf(wv - bf2f(h16));
    }
    *(sfrag *)&wlds_hi[(size_t)idx * 8] = vh;
    *(sfrag *)&wlds_lo[(size_t)idx * 8] = vl;
  }

  // epilogue thread mapping: bm = batch, um = unit-in-slice
  const int bm = tid >> 3;
  const int um = tid & 7;
  const int jg = slice * 8 + um;
  const float bia_i = p.bi[l * Hv + jg];
  const float bia_f = p.bf[l * Hv + jg];
  const float bia_o = p.bo[l * Hv + jg];
  const float bia_c = p.bc[l * Hv + jg];
  float cstate = 0.f;

  __syncthreads();

  const int m = mt * 16 + (lane & 15); // batch row for A fragment
  const int kgrp = lane >> 4;          // k-group 0..3
  int *flags = p.flags;
  unsigned short *hbuf = p.hbuf;
  const int per_slice = p.per_slice;

#define MFMA_BURST(A, KKB, CNT)                                                \
  {                                                                            \
    _Pragma("unroll") for (int j = 0; j < (CNT); ++j) {                        \
      sfrag bh =                                                               \
          *(const sfrag *)&wlds_hi[(size_t)((nt * NKK + (KKB) + j) * 64 + lane) * 8]; \
      sfrag bl =                                                               \
          *(const sfrag *)&wlds_lo[(size_t)((nt * NKK + (KKB) + j) * 64 + lane) * 8]; \
      acc0 = __builtin_amdgcn_mfma_f32_16x16x32_bf16(A[j], bh, acc0, 0, 0, 0); \
      acc1 = __builtin_amdgcn_mfma_f32_16x16x32_bf16(A[j], bl, acc1, 0, 0, 0); \
    }                                                                          \
  }

  for (int t = 0; t < Tv; ++t) {
    // ---- wait for dependencies via FRESH (bypass) flag reads ----
    if (per_slice) {
      if (t > 0 && tid < SLICES) {
        const int *fp = &flags[(t * LAYv + l) * SLICES + tid];
        bool got = false;
        while (!got) {
          got = (ld_flag_bypass(fp) != 0);
          if (!got) __builtin_amdgcn_s_sleep(1);
        }
      }
      if (l > 0 && tid >= 64 && tid < 64 + SLICES) {
        const int *fp = &flags[((t + 1) * LAYv + (l - 1)) * SLICES + (tid - 64)];
        bool got = false;
        while (!got) {
          got = (ld_flag_bypass(fp) != 0);
          if (!got) __builtin_amdgcn_s_sleep(1);
        }
      }
    } else {
      if (tid == 0) {
        if (t > 0) {
          const int *fp = &flags[t * LAYv + l];
          while (ld_flag_bypass(fp) < SLICES) __builtin_amdgcn_s_sleep(1);
        }
        if (l > 0) {
          const int *fp = &flags[(t + 1) * LAYv + (l - 1)];
          while (ld_flag_bypass(fp) < SLICES) __builtin_amdgcn_s_sleep(1);
        }
      }
    }
    __syncthreads();

    // ---- load A-fragments with bypass (fresh from MALL) ----
    const unsigned short *hrec =
        hbuf + ((size_t)(t * LAYv + l) * Bv * Hv) + (size_t)m * Hv;
    sfrag arec[16];
    ld_row_bypass(arec, hrec + kgrp * 8);

    facc acc0 = {0.f, 0.f, 0.f, 0.f};
    facc acc1 = {0.f, 0.f, 0.f, 0.f};

    if (l == 0) {
      MFMA_BURST(arec, 0, 16)
      const float *xbp = p.x + ((size_t)m * Tv + t) * Iv + kgrp * 8;
#pragma unroll
      for (int kk = 0; kk < 8; ++kk) {
        f32x4 lo = *(const f32x4 *)(xbp + kk * 32);
        f32x4 hi = *(const f32x4 *)(xbp + kk * 32 + 4);
        sfrag ax;
#pragma unroll
        for (int j = 0; j < 4; ++j) {
          ax[j] = (short)f2bf(lo[j]);
          ax[4 + j] = (short)f2bf(hi[j]);
        }
        sfrag bh = *(const sfrag *)&wlds_hi[(size_t)((nt * NKK + 16 + kk) * 64 + lane) * 8];
        sfrag bl = *(const sfrag *)&wlds_lo[(size_t)((nt * NKK + 16 + kk) * 64 + lane) * 8];
        acc0 = __builtin_amdgcn_mfma_f32_16x16x32_bf16(ax, bh, acc0, 0, 0, 0);
        acc1 = __builtin_amdgcn_mfma_f32_16x16x32_bf16(ax, bl, acc1, 0, 0, 0);
      }
    } else {
      const unsigned short *hin =
          hbuf + ((size_t)((t + 1) * LAYv + (l - 1)) * Bv * Hv) + (size_t)m * Hv;
      sfrag ain[16];
      ld_row_bypass(ain, hin + kgrp * 8);
      MFMA_BURST(arec, 0, 16)
      MFMA_BURST(ain, 16, 16)
    }

    // ---- scatter pre-activations to LDS ----
    {
      int row = mt * 16 + kgrp * 4;
      int coln = nt * 16 + (lane & 15);
#pragma unroll
      for (int r = 0; r < 4; ++r)
        preact[(row + r) * 33 + coln] = acc0[r] + acc1[r];
    }
    __syncthreads();

    // ---- gates / state update: one thread per (batch, unit) ----
    float pi = preact[bm * 33 + um * 4 + 0] + bia_i;
    float pf = preact[bm * 33 + um * 4 + 1] + bia_f;
    float po = preact[bm * 33 + um * 4 + 2] + bia_o;
    float pc = preact[bm * 33 + um * 4 + 3] + bia_c;
    float gi = 1.f / (1.f + __expf(-pi));
    float gf = 1.f / (1.f + __expf(-pf));
    float go = 1.f / (1.f + __expf(-po));
    float gc = tanhf(pc);
    cstate = gf * cstate + gi * gc;
    float hval = go * tanhf(cstate);

    // bypass store: write-through to the MALL coherence point
    st_short_bypass(
        &hbuf[(size_t)((t + 1) * LAYv + l) * Bv * Hv + (size_t)bm * Hv + jg],
        f2bf(hval));
    if (l == LAYv - 1)
      p.out[((size_t)bm * Tv + t) * Hv + jg] = hval;

    asm volatile("s_waitcnt vmcnt(0)" ::: "memory"); // h stores ack'd at MALL
    __syncthreads(); // all waves drained

    if (tid == 0) {
      if (per_slice)
        st_dword_bypass(&flags[((t + 1) * LAYv + l) * SLICES + slice], 1);
      else
        atomicAdd(&flags[(t + 1) * LAYv + l], 1); // RMW: fresh by definition
    }
  }
#undef MFMA_BURST
}

extern "C" void kernel_launch(void *const *d_in, const int *in_sizes, int n_in,
                              void *d_out, int out_size, void *d_ws, size_t ws_size,
                              hipStream_t stream) {
  Params prm;
  prm.x = (const float *)d_in[0];
  prm.Wx0i = (const float *)d_in[1];
  prm.Wx0f = (const float *)d_in[2];
  prm.Wx0o = (const float *)d_in[3];
  prm.Wx0c = (const float *)d_in[4];
  prm.Wxi = (const float *)d_in[5];
  prm.Wxf = (const float *)d_in[6];
  prm.Wxo = (const float *)d_in[7];
  prm.Wxc = (const float *)d_in[8];
  prm.Whi = (const float *)d_in[9];
  prm.Whf = (const float *)d_in[10];
  prm.Who = (const float *)d_in[11];
  prm.Whc = (const float *)d_in[12];
  prm.bi = (const float *)d_in[13];
  prm.bf = (const float *)d_in[14];
  prm.bo = (const float *)d_in[15];
  prm.bc = (const float *)d_in[16];
  prm.out = (float *)d_out;

  size_t hbytes = (size_t)(Tv + 1) * LAYv * Bv * Hv * sizeof(unsigned short);
  size_t f_small = (size_t)(Tv + 1) * LAYv * sizeof(int);
  size_t f_big = (size_t)(Tv + 1) * LAYv * SLICES * sizeof(int);
  if (ws_size < hbytes + f_small) return;
  prm.hbuf = (unsigned short *)d_ws;
  prm.flags = (int *)((char *)d_ws + hbytes);
  prm.per_slice = (ws_size >= hbytes + f_big) ? 1 : 0;
  size_t fbytes = prm.per_slice ? f_big : f_small;

  // reset flags and the t=0 zero h-slot every call (deterministic replays)
  hipMemsetAsync(prm.flags, 0, fbytes, stream);
  hipMemsetAsync(d_ws, 0, (size_t)LAYv * Bv * Hv * sizeof(unsigned short), stream);

  hipFuncSetAttribute(reinterpret_cast<const void *>(lstm_pipeline),
                      hipFuncAttributeMaxDynamicSharedMemorySize, (int)SMEM_BYTES);

  // Plain launch: 135KB LDS forces 1 block/CU; grid == 256 == #CUs, so all
  // blocks are co-resident.
  hipLaunchKernelGGL(lstm_pipeline, dim3(LAYv * SLICES), dim3(THREADS),
                     SMEM_BYTES, stream, prm);
}

// Round 7
// 4594.493 us; speedup vs baseline: 1.7274x; 1.0562x over previous
//
#include <hip/hip_runtime.h>

// DeepLSTM persistent wavefront pipeline for MI355X (gfx950).
// 256 WGs (1/CU): layer = blockIdx/64, slice of 8 hidden units = blockIdx%64.
// Weights resident in LDS as hi/lo bf16 split.
// R7: control path (flags) stays full-bypass sc0+sc1; h DATA loads are now
// plain CACHED loads. Safe because hbuf slots are write-once, consumers only
// read after all 64 producer flags are MALL-visible (so no partial lines get
// cached), and kernel-boundary invalidation guarantees no stale lines at
// start. This kills the ~128x MALL broadcast amplification (each XCD fetches
// each h panel once; 31 other CUs hit XCD L2) that was congesting the MALL
// and inflating every round trip (flag polls included) to ~us.

constexpr int Bv = 32;
constexpr int Tv = 512;
constexpr int Iv = 256;
constexpr int Hv = 512;
constexpr int LAYv = 4;
constexpr int SLICES = 64;   // WGs per layer
constexpr int THREADS = 256; // 4 waves
constexpr int NKK = 32;      // max K/32 (512 recurrent + 512 input)
constexpr int WTAB = 2 * NKK * 64 * 8;            // shorts per weight table (32768)
constexpr unsigned SMEM_BYTES = WTAB * 2 * 2 + 32 * 33 * 4; // 135296

typedef short sfrag __attribute__((ext_vector_type(8)));
typedef float facc  __attribute__((ext_vector_type(4)));
typedef float f32x4 __attribute__((ext_vector_type(4)));

struct Params {
  const float *x;
  const float *Wx0i, *Wx0f, *Wx0o, *Wx0c;
  const float *Wxi, *Wxf, *Wxo, *Wxc;
  const float *Whi, *Whf, *Who, *Whc;
  const float *bi, *bf, *bo, *bc;
  float *out;
  unsigned short *hbuf; // [(T+1)][L][B][H] bf16 slots, write-once per slot
  int *flags;           // per_slice: [(T+1)][L][SLICES] else [(T+1)][L]
  int per_slice;
};

__device__ __forceinline__ unsigned short f2bf(float f) {
  unsigned int u = __builtin_bit_cast(unsigned int, f);
  u += 0x7FFFu + ((u >> 16) & 1u); // RNE
  return (unsigned short)(u >> 16);
}
__device__ __forceinline__ float bf2f(unsigned short s) {
  unsigned int u = ((unsigned int)s) << 16;
  return __builtin_bit_cast(float, u);
}

// ---- full-bypass (L1+L2) control-path primitives ----
__device__ __forceinline__ int ld_flag_bypass(const int *p) {
  int v;
  asm volatile("global_load_dword %0, %1, off sc0 sc1\n\t"
               "s_waitcnt vmcnt(0)"
               : "=v"(v) : "v"(p) : "memory");
  return v;
}
__device__ __forceinline__ void st_short_bypass(unsigned short *p, unsigned short v) {
  asm volatile("global_store_short %0, %1, off sc0 sc1" ::"v"(p), "v"(v)
               : "memory");
}
__device__ __forceinline__ void st_dword_bypass(int *p, int v) {
  asm volatile("global_store_dword %0, %1, off sc0 sc1" ::"v"(p), "v"(v)
               : "memory");
}

__global__ void __launch_bounds__(THREADS, 1) lstm_pipeline(Params p) {
  const int wg = blockIdx.x;
  const int l = wg >> 6;       // layer 0..3
  const int slice = wg & 63;   // 8-unit slice
  const int tid = threadIdx.x;
  const int lane = tid & 63;
  const int w = tid >> 6;      // wave 0..3
  const int mt = w & 1;        // M-tile (batch 16-block)
  const int nt = w >> 1;       // N-tile (gate-col 16-block)

  extern __shared__ char smem[];
  unsigned short *wlds_hi = (unsigned short *)smem;          // [2][32][64][8]
  unsigned short *wlds_lo = wlds_hi + WTAB;
  float *preact = (float *)(smem + (size_t)WTAB * 2 * 2);    // [32][33]

  // gate-indexed weight bases for this layer
  const float *Wh[4] = {p.Whi + (size_t)l * Hv * Hv, p.Whf + (size_t)l * Hv * Hv,
                        p.Who + (size_t)l * Hv * Hv, p.Whc + (size_t)l * Hv * Hv};
  const float *Wx[4];
  if (l == 0) { Wx[0] = p.Wx0i; Wx[1] = p.Wx0f; Wx[2] = p.Wx0o; Wx[3] = p.Wx0c; }
  else {
    size_t o = (size_t)(l - 1) * Hv * Hv;
    Wx[0] = p.Wxi + o; Wx[1] = p.Wxf + o; Wx[2] = p.Wxo + o; Wx[3] = p.Wxc + o;
  }
  const int kx_max = (l == 0) ? Iv : Hv;

  // ---- stage weight slice into LDS in MFMA B-fragment order (hi/lo split) ----
  for (int idx = tid; idx < 2 * NKK * 64; idx += THREADS) {
    int lanei = idx & 63;
    int kk = (idx >> 6) & (NKK - 1);
    int nti = idx >> 11;
    int kbase = kk * 32 + (lanei >> 4) * 8;
    int n = nti * 16 + (lanei & 15); // gate-col within 32: n = jj*4 + g
    int jj = n >> 2, g = n & 3;
    int col = slice * 8 + jj;
    sfrag vh, vl;
#pragma unroll
    for (int j = 0; j < 8; ++j) {
      int k = kbase + j;
      float wv;
      if (k < Hv) wv = Wh[g][(size_t)k * Hv + col];
      else {
        int kx = k - Hv;
        wv = (kx < kx_max) ? Wx[g][(size_t)kx * Hv + col] : 0.f;
      }
      unsigned short h16 = f2bf(wv);
      vh[j] = (short)h16;
      vl[j] = (short)f2bf(wv - bf2f(h16));
    }
    *(sfrag *)&wlds_hi[(size_t)idx * 8] = vh;
    *(sfrag *)&wlds_lo[(size_t)idx * 8] = vl;
  }

  // epilogue thread mapping: bm = batch, um = unit-in-slice
  const int bm = tid >> 3;
  const int um = tid & 7;
  const int jg = slice * 8 + um;
  const float bia_i = p.bi[l * Hv + jg];
  const float bia_f = p.bf[l * Hv + jg];
  const float bia_o = p.bo[l * Hv + jg];
  const float bia_c = p.bc[l * Hv + jg];
  float cstate = 0.f;

  __syncthreads();

  const int m = mt * 16 + (lane & 15); // batch row for A fragment
  const int kgrp = lane >> 4;          // k-group 0..3
  int *flags = p.flags;
  unsigned short *hbuf = p.hbuf;
  const int per_slice = p.per_slice;

#define MFMA_BURST(A, KKB, CNT)                                                \
  {                                                                            \
    _Pragma("unroll") for (int j = 0; j < (CNT); ++j) {                        \
      sfrag bh =                                                               \
          *(const sfrag *)&wlds_hi[(size_t)((nt * NKK + (KKB) + j) * 64 + lane) * 8]; \
      sfrag bl =                                                               \
          *(const sfrag *)&wlds_lo[(size_t)((nt * NKK + (KKB) + j) * 64 + lane) * 8]; \
      acc0 = __builtin_amdgcn_mfma_f32_16x16x32_bf16(A[j], bh, acc0, 0, 0, 0); \
      acc1 = __builtin_amdgcn_mfma_f32_16x16x32_bf16(A[j], bl, acc1, 0, 0, 0); \
    }                                                                          \
  }

  for (int t = 0; t < Tv; ++t) {
    // ---- wait for dependencies via FRESH (bypass) flag reads.
    // Full-layer wait BEFORE any cached h load: guarantees every 64B
    // segment of the h panel is complete at the MALL, so cached lines
    // can never be partially valid.
    if (per_slice) {
      if (t > 0 && tid < SLICES) {
        const int *fp = &flags[(t * LAYv + l) * SLICES + tid];
        bool got = false;
        while (!got) {
          got = (ld_flag_bypass(fp) != 0);
          if (!got) __builtin_amdgcn_s_sleep(4);
        }
      }
      if (l > 0 && tid >= 64 && tid < 64 + SLICES) {
        const int *fp = &flags[((t + 1) * LAYv + (l - 1)) * SLICES + (tid - 64)];
        bool got = false;
        while (!got) {
          got = (ld_flag_bypass(fp) != 0);
          if (!got) __builtin_amdgcn_s_sleep(4);
        }
      }
    } else {
      if (tid == 0) {
        if (t > 0) {
          const int *fp = &flags[t * LAYv + l];
          while (ld_flag_bypass(fp) < SLICES) __builtin_amdgcn_s_sleep(4);
        }
        if (l > 0) {
          const int *fp = &flags[(t + 1) * LAYv + (l - 1)];
          while (ld_flag_bypass(fp) < SLICES) __builtin_amdgcn_s_sleep(4);
        }
      }
    }
    __syncthreads();

    // ---- load A-fragments with plain CACHED loads (XCD-L2 broadcast) ----
    const unsigned short *hrec =
        hbuf + ((size_t)(t * LAYv + l) * Bv * Hv) + (size_t)m * Hv;
    sfrag arec[16];
#pragma unroll
    for (int kk = 0; kk < 16; ++kk)
      arec[kk] = *(const sfrag *)(hrec + kk * 32 + kgrp * 8);

    facc acc0 = {0.f, 0.f, 0.f, 0.f};
    facc acc1 = {0.f, 0.f, 0.f, 0.f};

    if (l == 0) {
      MFMA_BURST(arec, 0, 16)
      const float *xbp = p.x + ((size_t)m * Tv + t) * Iv + kgrp * 8;
#pragma unroll
      for (int kk = 0; kk < 8; ++kk) {
        f32x4 lo = *(const f32x4 *)(xbp + kk * 32);
        f32x4 hi = *(const f32x4 *)(xbp + kk * 32 + 4);
        sfrag ax;
#pragma unroll
        for (int j = 0; j < 4; ++j) {
          ax[j] = (short)f2bf(lo[j]);
          ax[4 + j] = (short)f2bf(hi[j]);
        }
        sfrag bh = *(const sfrag *)&wlds_hi[(size_t)((nt * NKK + 16 + kk) * 64 + lane) * 8];
        sfrag bl = *(const sfrag *)&wlds_lo[(size_t)((nt * NKK + 16 + kk) * 64 + lane) * 8];
        acc0 = __builtin_amdgcn_mfma_f32_16x16x32_bf16(ax, bh, acc0, 0, 0, 0);
        acc1 = __builtin_amdgcn_mfma_f32_16x16x32_bf16(ax, bl, acc1, 0, 0, 0);
      }
    } else {
      const unsigned short *hin =
          hbuf + ((size_t)((t + 1) * LAYv + (l - 1)) * Bv * Hv) + (size_t)m * Hv;
      sfrag ain[16];
#pragma unroll
      for (int kk = 0; kk < 16; ++kk)
        ain[kk] = *(const sfrag *)(hin + kk * 32 + kgrp * 8);
      MFMA_BURST(arec, 0, 16)
      MFMA_BURST(ain, 16, 16)
    }

    // ---- scatter pre-activations to LDS ----
    {
      int row = mt * 16 + kgrp * 4;
      int coln = nt * 16 + (lane & 15);
#pragma unroll
      for (int r = 0; r < 4; ++r)
        preact[(row + r) * 33 + coln] = acc0[r] + acc1[r];
    }
    __syncthreads();

    // ---- gates / state update: one thread per (batch, unit) ----
    float pi = preact[bm * 33 + um * 4 + 0] + bia_i;
    float pf = preact[bm * 33 + um * 4 + 1] + bia_f;
    float po = preact[bm * 33 + um * 4 + 2] + bia_o;
    float pc = preact[bm * 33 + um * 4 + 3] + bia_c;
    float gi = 1.f / (1.f + __expf(-pi));
    float gf = 1.f / (1.f + __expf(-pf));
    float go = 1.f / (1.f + __expf(-po));
    float gc = tanhf(pc);
    cstate = gf * cstate + gi * gc;
    float hval = go * tanhf(cstate);

    // bypass store: write-through to the MALL coherence point
    st_short_bypass(
        &hbuf[(size_t)((t + 1) * LAYv + l) * Bv * Hv + (size_t)bm * Hv + jg],
        f2bf(hval));
    if (l == LAYv - 1)
      p.out[((size_t)bm * Tv + t) * Hv + jg] = hval;

    asm volatile("s_waitcnt vmcnt(0)" ::: "memory"); // h stores ack'd at MALL
    __syncthreads(); // all waves drained

    if (tid == 0) {
      if (per_slice)
        st_dword_bypass(&flags[((t + 1) * LAYv + l) * SLICES + slice], 1);
      else
        atomicAdd(&flags[(t + 1) * LAYv + l], 1); // RMW: fresh by definition
    }
  }
#undef MFMA_BURST
}

extern "C" void kernel_launch(void *const *d_in, const int *in_sizes, int n_in,
                              void *d_out, int out_size, void *d_ws, size_t ws_size,
                              hipStream_t stream) {
  Params prm;
  prm.x = (const float *)d_in[0];
  prm.Wx0i = (const float *)d_in[1];
  prm.Wx0f = (const float *)d_in[2];
  prm.Wx0o = (const float *)d_in[3];
  prm.Wx0c = (const float *)d_in[4];
  prm.Wxi = (const float *)d_in[5];
  prm.Wxf = (const float *)d_in[6];
  prm.Wxo = (const float *)d_in[7];
  prm.Wxc = (const float *)d_in[8];
  prm.Whi = (const float *)d_in[9];
  prm.Whf = (const float *)d_in[10];
  prm.Who = (const float *)d_in[11];
  prm.Whc = (const float *)d_in[12];
  prm.bi = (const float *)d_in[13];
  prm.bf = (const float *)d_in[14];
  prm.bo = (const float *)d_in[15];
  prm.bc = (const float *)d_in[16];
  prm.out = (float *)d_out;

  size_t hbytes = (size_t)(Tv + 1) * LAYv * Bv * Hv * sizeof(unsigned short);
  size_t f_small = (size_t)(Tv + 1) * LAYv * sizeof(int);
  size_t f_big = (size_t)(Tv + 1) * LAYv * SLICES * sizeof(int);
  if (ws_size < hbytes + f_small) return;
  prm.hbuf = (unsigned short *)d_ws;
  prm.flags = (int *)((char *)d_ws + hbytes);
  prm.per_slice = (ws_size >= hbytes + f_big) ? 1 : 0;
  size_t fbytes = prm.per_slice ? f_big : f_small;

  // reset flags and the t=0 zero h-slot every call (deterministic replays)
  hipMemsetAsync(prm.flags, 0, fbytes, stream);
  hipMemsetAsync(d_ws, 0, (size_t)LAYv * Bv * Hv * sizeof(unsigned short), stream);

  hipFuncSetAttribute(reinterpret_cast<const void *>(lstm_pipeline),
                      hipFuncAttributeMaxDynamicSharedMemorySize, (int)SMEM_BYTES);

  // Plain launch: 135KB LDS forces 1 block/CU; grid == 256 == #CUs, so all
  // blocks are co-resident.
  hipLaunchKernelGGL(lstm_pipeline, dim3(LAYv * SLICES), dim3(THREADS),
                     SMEM_BYTES, stream, prm);
}

// Round 8
// 3522.411 us; speedup vs baseline: 2.2531x; 1.3044x over previous
//
#include <hip/hip_runtime.h>

// DeepLSTM persistent wavefront pipeline for MI355X (gfx950).
// 256 WGs (1/CU): layer = blockIdx/64, slice of 8 hidden units = blockIdx%64.
// Weights resident in LDS as hi/lo bf16 split. Control path = sc0/sc1 bypass;
// h data loads = plain cached (read-once addresses -> no staleness).
// R8: wave-decoupled hop. Per-(wave,slice) byte flags: each producer wave
// drains its own stores (vmcnt is per-wave) and posts its own flag -- no
// epilogue barrier. Consumer waves poll only the 128 flags covering their 16
// batch rows (2 coalesced byte loads/lane). ONE __syncthreads per step
// (scatter->epilogue), preact double-buffered. Input-half GEMM runs before
// the recurrent poll (off critical path). t=0 recurrent GEMM skipped (h0=0),
// making hbuf an exactly-once-read 512-slot ring.

constexpr int Bv = 32;
constexpr int Tv = 512;
constexpr int Iv = 256;
constexpr int Hv = 512;
constexpr int LAYv = 4;
constexpr int SLICES = 64;   // WGs per layer
constexpr int THREADS = 256; // 4 waves
constexpr int NKK = 32;      // K/32 total (512 recurrent + 512 input)
constexpr int WTAB = 2 * NKK * 64 * 8;  // shorts per weight table
constexpr int PRE = 32 * 33;
constexpr unsigned SMEM_BYTES = WTAB * 2 * 2 + 2 * PRE * 4; // 139520

typedef short sfrag __attribute__((ext_vector_type(8)));
typedef float facc  __attribute__((ext_vector_type(4)));
typedef float f32x4 __attribute__((ext_vector_type(4)));

struct Params {
  const float *x;
  const float *Wx0i, *Wx0f, *Wx0o, *Wx0c;
  const float *Wxi, *Wxf, *Wxo, *Wxc;
  const float *Whi, *Whf, *Who, *Whc;
  const float *bi, *bf, *bo, *bc;
  float *out;
  unsigned short *hbuf;  // ring [dmask+1 t-slots][L][B][H] bf16
  unsigned char *flags;  // [Tv*L][4 waves][64 slices], write-once, bypass
  int dmask;             // hbuf ring mask on t (511 primary)
};

__device__ __forceinline__ unsigned short f2bf(float f) {
  unsigned int u = __builtin_bit_cast(unsigned int, f);
  u += 0x7FFFu + ((u >> 16) & 1u); // RNE
  return (unsigned short)(u >> 16);
}
__device__ __forceinline__ float bf2f(unsigned short s) {
  unsigned int u = ((unsigned int)s) << 16;
  return __builtin_bit_cast(float, u);
}

// ---- bypass (L1+L2) control-path primitives ----
__device__ __forceinline__ int ld_flagb_bypass(const unsigned char *p) {
  int v;
  asm volatile("global_load_ubyte %0, %1, off sc0 sc1\n\t"
               "s_waitcnt vmcnt(0)"
               : "=v"(v) : "v"(p) : "memory");
  return v;
}
__device__ __forceinline__ void st_flagb_bypass(unsigned char *p) {
  asm volatile("global_store_byte %0, %1, off sc0 sc1" ::"v"(p), "v"(1)
               : "memory");
}
__device__ __forceinline__ void st_short_bypass(unsigned short *p, unsigned short v) {
  asm volatile("global_store_short %0, %1, off sc0 sc1" ::"v"(p), "v"(v)
               : "memory");
}
// poll the 2 producer-wave flag rows covering this consumer wave's 16 rows
__device__ __forceinline__ void poll_pair(const unsigned char *f0) {
  while (ld_flagb_bypass(f0) == 0) __builtin_amdgcn_s_sleep(1);
  while (ld_flagb_bypass(f0 + 64) == 0) __builtin_amdgcn_s_sleep(1);
}

__global__ void __launch_bounds__(THREADS, 1) lstm_pipeline(Params p) {
  const int wg = blockIdx.x;
  const int l = wg >> 6;       // layer 0..3
  const int slice = wg & 63;   // 8-unit slice
  const int tid = threadIdx.x;
  const int lane = tid & 63;
  const int w = tid >> 6;      // wave 0..3
  const int mt = w & 1;        // M-tile (batch 16-block)
  const int nt = w >> 1;       // N-tile (gate-col 16-block)

  extern __shared__ char smem[];
  unsigned short *wlds_hi = (unsigned short *)smem;       // [2][32][64][8]
  unsigned short *wlds_lo = wlds_hi + WTAB;
  float *pre0 = (float *)(smem + (size_t)WTAB * 2 * 2);   // [2][32][33]

  // gate-indexed weight bases for this layer
  const float *Wh[4] = {p.Whi + (size_t)l * Hv * Hv, p.Whf + (size_t)l * Hv * Hv,
                        p.Who + (size_t)l * Hv * Hv, p.Whc + (size_t)l * Hv * Hv};
  const float *Wx[4];
  if (l == 0) { Wx[0] = p.Wx0i; Wx[1] = p.Wx0f; Wx[2] = p.Wx0o; Wx[3] = p.Wx0c; }
  else {
    size_t o = (size_t)(l - 1) * Hv * Hv;
    Wx[0] = p.Wxi + o; Wx[1] = p.Wxf + o; Wx[2] = p.Wxo + o; Wx[3] = p.Wxc + o;
  }
  const int kx_max = (l == 0) ? Iv : Hv;

  // ---- stage weight slice into LDS in MFMA B-fragment order (hi/lo split) ----
  for (int idx = tid; idx < 2 * NKK * 64; idx += THREADS) {
    int lanei = idx & 63;
    int kk = (idx >> 6) & (NKK - 1);
    int nti = idx >> 11;
    int kbase = kk * 32 + (lanei >> 4) * 8;
    int n = nti * 16 + (lanei & 15); // gate-col within 32: n = jj*4 + g
    int jj = n >> 2, g = n & 3;
    int col = slice * 8 + jj;
    sfrag vh, vl;
#pragma unroll
    for (int j = 0; j < 8; ++j) {
      int k = kbase + j;
      float wv;
      if (k < Hv) wv = Wh[g][(size_t)k * Hv + col];
      else {
        int kx = k - Hv;
        wv = (kx < kx_max) ? Wx[g][(size_t)kx * Hv + col] : 0.f;
      }
      unsigned short h16 = f2bf(wv);
      vh[j] = (short)h16;
      vl[j] = (short)f2bf(wv - bf2f(h16));
    }
    *(sfrag *)&wlds_hi[(size_t)idx * 8] = vh;
    *(sfrag *)&wlds_lo[(size_t)idx * 8] = vl;
  }

  // epilogue thread mapping: bm = batch, um = unit-in-slice
  const int bm = tid >> 3;
  const int um = tid & 7;
  const int jg = slice * 8 + um;
  const float bia_i = p.bi[l * Hv + jg];
  const float bia_f = p.bf[l * Hv + jg];
  const float bia_o = p.bo[l * Hv + jg];
  const float bia_c = p.bc[l * Hv + jg];
  float cstate = 0.f;

  __syncthreads();

  const int m = mt * 16 + (lane & 15); // batch row for A fragment
  const int kgrp = lane >> 4;          // k-group 0..3
  unsigned char *flags = p.flags;
  unsigned short *hbuf = p.hbuf;
  const int dmask = p.dmask;

#define MFMA_BURST(A, KKB, CNT)                                                \
  {                                                                            \
    _Pragma("unroll") for (int j = 0; j < (CNT); ++j) {                        \
      sfrag bh =                                                               \
          *(const sfrag *)&wlds_hi[(size_t)((nt * NKK + (KKB) + j) * 64 + lane) * 8]; \
      sfrag bl =                                                               \
          *(const sfrag *)&wlds_lo[(size_t)((nt * NKK + (KKB) + j) * 64 + lane) * 8]; \
      acc0 = __builtin_amdgcn_mfma_f32_16x16x32_bf16(A[j], bh, acc0, 0, 0, 0); \
      acc1 = __builtin_amdgcn_mfma_f32_16x16x32_bf16(A[j], bl, acc1, 0, 0, 0); \
    }                                                                          \
  }

  for (int t = 0; t < Tv; ++t) {
    facc acc0 = {0.f, 0.f, 0.f, 0.f};
    facc acc1 = {0.f, 0.f, 0.f, 0.f};

    // ================= input half (off critical path) =================
    if (l == 0) {
      const float *xbp = p.x + ((size_t)m * Tv + t) * Iv + kgrp * 8;
#pragma unroll
      for (int kk = 0; kk < 8; ++kk) {
        f32x4 lo = *(const f32x4 *)(xbp + kk * 32);
        f32x4 hi = *(const f32x4 *)(xbp + kk * 32 + 4);
        sfrag ax;
#pragma unroll
        for (int j = 0; j < 4; ++j) {
          ax[j] = (short)f2bf(lo[j]);
          ax[4 + j] = (short)f2bf(hi[j]);
        }
        sfrag bh = *(const sfrag *)&wlds_hi[(size_t)((nt * NKK + 16 + kk) * 64 + lane) * 8];
        sfrag bl = *(const sfrag *)&wlds_lo[(size_t)((nt * NKK + 16 + kk) * 64 + lane) * 8];
        acc0 = __builtin_amdgcn_mfma_f32_16x16x32_bf16(ax, bh, acc0, 0, 0, 0);
        acc1 = __builtin_amdgcn_mfma_f32_16x16x32_bf16(ax, bl, acc1, 0, 0, 0);
      }
    } else {
      // h_{l-1}[t+1]: produced ~1 hop earlier; flags usually already set
      poll_pair(flags + ((size_t)(t * LAYv + (l - 1))) * 256 + (2 * mt) * 64 + lane);
      const unsigned short *hin =
          hbuf + ((size_t)(((t + 1) & dmask) * LAYv + (l - 1)) * Bv * Hv) +
          (size_t)m * Hv;
      sfrag ain[16];
#pragma unroll
      for (int kk = 0; kk < 16; ++kk)
        ain[kk] = *(const sfrag *)(hin + kk * 32 + kgrp * 8);
      MFMA_BURST(ain, 16, 16)
    }

    // ================= recurrent half (critical path) =================
    if (t > 0) {
      poll_pair(flags + ((size_t)((t - 1) * LAYv + l)) * 256 + (2 * mt) * 64 + lane);
      const unsigned short *hrec =
          hbuf + ((size_t)((t & dmask) * LAYv + l) * Bv * Hv) + (size_t)m * Hv;
      sfrag arec[16];
#pragma unroll
      for (int kk = 0; kk < 16; ++kk)
        arec[kk] = *(const sfrag *)(hrec + kk * 32 + kgrp * 8);
      MFMA_BURST(arec, 0, 16)
    } // t==0: h=0 contributes nothing -- skip (also keeps ring read-once)

    // ---- scatter pre-activations to double-buffered LDS ----
    float *pa = pre0 + (t & 1) * PRE;
    {
      int row = mt * 16 + kgrp * 4;
      int coln = nt * 16 + (lane & 15);
#pragma unroll
      for (int r = 0; r < 4; ++r)
        pa[(row + r) * 33 + coln] = acc0[r] + acc1[r];
    }
    __syncthreads(); // the ONLY barrier per step

    // ---- gates / state update: one thread per (batch, unit) ----
    float pi = pa[bm * 33 + um * 4 + 0] + bia_i;
    float pf = pa[bm * 33 + um * 4 + 1] + bia_f;
    float po = pa[bm * 33 + um * 4 + 2] + bia_o;
    float pc = pa[bm * 33 + um * 4 + 3] + bia_c;
    float gi = 1.f / (1.f + __expf(-pi));
    float gf = 1.f / (1.f + __expf(-pf));
    float go = 1.f / (1.f + __expf(-po));
    float gc = tanhf(pc);
    cstate = gf * cstate + gi * gc;
    float hval = go * tanhf(cstate);

    // bypass store h[t+1]; per-WAVE drain; per-wave flag (rows 8w..8w+7)
    st_short_bypass(
        &hbuf[((size_t)(((t + 1) & dmask) * LAYv + l) * Bv * Hv) +
              (size_t)bm * Hv + jg],
        f2bf(hval));
    asm volatile("s_waitcnt vmcnt(0)" ::: "memory"); // this wave's stores at MALL
    if (lane == 0)
      st_flagb_bypass(flags + ((size_t)(t * LAYv + l)) * 256 + w * 64 + slice);

    if (l == LAYv - 1) // off critical path, after flag
      p.out[((size_t)bm * Tv + t) * Hv + jg] = hval;
  }
#undef MFMA_BURST
}

extern "C" void kernel_launch(void *const *d_in, const int *in_sizes, int n_in,
                              void *d_out, int out_size, void *d_ws, size_t ws_size,
                              hipStream_t stream) {
  Params prm;
  prm.x = (const float *)d_in[0];
  prm.Wx0i = (const float *)d_in[1];
  prm.Wx0f = (const float *)d_in[2];
  prm.Wx0o = (const float *)d_in[3];
  prm.Wx0c = (const float *)d_in[4];
  prm.Wxi = (const float *)d_in[5];
  prm.Wxf = (const float *)d_in[6];
  prm.Wxo = (const float *)d_in[7];
  prm.Wxc = (const float *)d_in[8];
  prm.Whi = (const float *)d_in[9];
  prm.Whf = (const float *)d_in[10];
  prm.Who = (const float *)d_in[11];
  prm.Whc = (const float *)d_in[12];
  prm.bi = (const float *)d_in[13];
  prm.bf = (const float *)d_in[14];
  prm.bo = (const float *)d_in[15];
  prm.bc = (const float *)d_in[16];
  prm.out = (float *)d_out;

  size_t slot_bytes = (size_t)LAYv * Bv * Hv * sizeof(unsigned short); // 128KB
  size_t fbytes = (size_t)Tv * LAYv * 4 * SLICES;                      // 512KB
  size_t hslots = 512; // exactly-once-read ring (t=0 never stored/read)
  if (ws_size < hslots * slot_bytes + fbytes) {
    hslots = 256; // fallback: slots reused once, 256 hops apart (L2 churn
                  // makes stale hits implausible; only if ws is tight)
    if (ws_size < hslots * slot_bytes + fbytes) return;
  }
  prm.dmask = (int)hslots - 1;
  prm.hbuf = (unsigned short *)d_ws;
  prm.flags = (unsigned char *)d_ws + hslots * slot_bytes;

  // write-once flags, cleared every call (deterministic replays)
  hipMemsetAsync(prm.flags, 0, fbytes, stream);

  hipFuncSetAttribute(reinterpret_cast<const void *>(lstm_pipeline),
                      hipFuncAttributeMaxDynamicSharedMemorySize, (int)SMEM_BYTES);

  // Plain launch: 139.5KB LDS forces 1 block/CU; grid == 256 == #CUs.
  hipLaunchKernelGGL(lstm_pipeline, dim3(LAYv * SLICES), dim3(THREADS),
                     SMEM_BYTES, stream, prm);
}